// Round 1
// baseline (320.053 us; speedup 1.0000x reference)
//
#include <hip/hip_runtime.h>
#include <math.h>

// PerBandSoftAGC: out = x / (clip(EMA_FIR(|x|), eps)^alpha + delta)
// EMA FIR (L=100, geometric weights) computed via exact sliding recursion:
//   M[t] = (1-s)*M[t-1] + w0*|x[t]| - w0*(1-s)^100 * |x[t-100]|
// One block per (b,kc) row; row staged in skewed LDS; 32 consecutive t per thread.

constexpr int T      = 8192;
constexpr int KC_    = 128;
constexpr int LEN    = 100;
constexpr int BLOCK  = 256;
constexpr int CHUNK  = 32;          // T / BLOCK
constexpr float EPS_   = 1e-6f;
constexpr float DELTA_ = 0.1f;

// skew: +1 float per 32 floats so stride-32-element lane access is conflict-free
__device__ __forceinline__ int skew(int t) { return t + (t >> 5); }

__global__ __launch_bounds__(BLOCK, 4) void agc_kernel(
    const float* __restrict__ x,
    const float* __restrict__ alpha_raw,
    const float* __restrict__ log_s,
    float* __restrict__ out)
{
    __shared__ float lx[T + (T >> 5)];   // 8448 floats = 33792 B -> 4 blocks/CU

    const int row = blockIdx.x;
    const int kc  = row & (KC_ - 1);
    const int tid = threadIdx.x;
    const float* __restrict__ xrow = x + (size_t)row * T;
    float* __restrict__ orow       = out + (size_t)row * T;

    // ---- stage row into skewed LDS (coalesced float4 global reads) ----
    #pragma unroll
    for (int it = 0; it < (T / 4) / BLOCK; ++it) {
        const int i = tid + it * BLOCK;
        const float4 v = reinterpret_cast<const float4*>(xrow)[i];
        const int a = skew(i * 4);       // 4 floats never cross a 32-boundary
        lx[a]     = v.x;
        lx[a + 1] = v.y;
        lx[a + 2] = v.z;
        lx[a + 3] = v.w;
    }

    // ---- per-channel scalars (block-uniform; redundant per thread, cheap) ----
    const float s     = 1.0f / (1.0f + __expf(-log_s[kc]));
    const float alpha = 0.5f / (1.0f + __expf(-alpha_raw[kc]));
    const float q     = 1.0f - s;
    float q100 = 1.0f;
    #pragma unroll
    for (int j = 0; j < LEN; ++j) q100 *= q;      // matches ref's iterative fp32 build closely
    const float norm = (1.0f - q100) + 1e-8f;     // sum of unnormalized geometric weights
    const float w0   = s / norm;                  // normalized weight j=0
    const float c3   = w0 * q100;                 // tail-drop coefficient

    __syncthreads();

    // ---- direct evaluation of M at chunk start (<=100 taps) ----
    const int t0 = tid * CHUNK;
    float M = 0.0f;
    {
        float wj = w0;
        const int jmax = (t0 >= LEN - 1) ? LEN : (t0 + 1);  // clip at row start
        for (int j = 0; j < jmax; ++j) {
            M += wj * fabsf(lx[skew(t0 - j)]);
            wj *= q;
        }
    }

    // ---- recursion + epilogue over the thread's 32 elements ----
    float xv = lx[skew(t0)];
    #pragma unroll
    for (int k4 = 0; k4 < CHUNK / 4; ++k4) {
        float4 o;
        float* op = &o.x;
        #pragma unroll
        for (int u = 0; u < 4; ++u) {
            const int k = k4 * 4 + u;
            const int t = t0 + k;
            if (k > 0) {
                xv = lx[skew(t)];
                const int tb = t - LEN;
                const float xb = (tb >= 0) ? fabsf(lx[skew(tb)]) : 0.0f;
                M = q * M + w0 * fabsf(xv) - c3 * xb;
            }
            const float Mc = fmaxf(M, EPS_);
            const float g  = __powf(Mc, alpha) + DELTA_;   // exp2(alpha*log2(Mc))
            op[u] = xv * __builtin_amdgcn_rcpf(g);         // g >= 0.1, rcp is safe
        }
        reinterpret_cast<float4*>(orow)[(t0 >> 2) + k4] = o;  // 16B aligned
    }
}

extern "C" void kernel_launch(void* const* d_in, const int* in_sizes, int n_in,
                              void* d_out, int out_size, void* d_ws, size_t ws_size,
                              hipStream_t stream) {
    const float* x         = (const float*)d_in[0];
    const float* alpha_raw = (const float*)d_in[1];
    const float* log_s     = (const float*)d_in[2];
    float* out             = (float*)d_out;
    const int nrows = in_sizes[0] / T;   // B*KC = 4096
    agc_kernel<<<nrows, BLOCK, 0, stream>>>(x, alpha_raw, log_s, out);
}

// Round 2
// 266.810 us; speedup vs baseline: 1.1996x; 1.1996x over previous
//
#include <hip/hip_runtime.h>
#include <math.h>

// PerBandSoftAGC: out = x / (clip(EMA_FIR(|x|), eps)^alpha + delta)
// EMA FIR (L=100, geometric weights) via exact sliding recursion:
//   M[t] = (1-s)*M[t-1] + w0*|x[t]| - w0*(1-s)^100 * |x[t-100]|
// R2: replaced __powf (HIP maps it to full-precision ocml pow, ~80 inst/elt —
// R1 was 95% VALUBusy because of it) with native v_log_f32/v_exp_f32.

constexpr int T      = 8192;
constexpr int KC_    = 128;
constexpr int LEN    = 100;
constexpr int BLOCK  = 256;
constexpr int CHUNK  = 32;          // T / BLOCK
constexpr float EPS_   = 1e-6f;
constexpr float DELTA_ = 0.1f;
constexpr float LOG2E  = 1.4426950408889634f;

// skew: +1 float per 32 floats so stride-32-element lane access is conflict-free
__device__ __forceinline__ int skew(int t) { return t + (t >> 5); }

__device__ __forceinline__ float fast_sigmoid(float x) {
    // 1/(1+2^(-x*log2e)) via native exp2 + rcp
    const float e = __builtin_amdgcn_exp2f(-x * LOG2E);
    return __builtin_amdgcn_rcpf(1.0f + e);
}

__global__ __launch_bounds__(BLOCK, 4) void agc_kernel(
    const float* __restrict__ x,
    const float* __restrict__ alpha_raw,
    const float* __restrict__ log_s,
    float* __restrict__ out)
{
    __shared__ float lx[T + (T >> 5)];   // 8448 floats = 33792 B -> 4 blocks/CU

    const int row = blockIdx.x;
    const int kc  = row & (KC_ - 1);
    const int tid = threadIdx.x;
    const float* __restrict__ xrow = x + (size_t)row * T;
    float* __restrict__ orow       = out + (size_t)row * T;

    // ---- stage row into skewed LDS (coalesced float4 global reads) ----
    #pragma unroll
    for (int it = 0; it < (T / 4) / BLOCK; ++it) {
        const int i = tid + it * BLOCK;
        const float4 v = reinterpret_cast<const float4*>(xrow)[i];
        const int a = skew(i * 4);       // 4 floats never cross a 32-boundary
        lx[a]     = v.x;
        lx[a + 1] = v.y;
        lx[a + 2] = v.z;
        lx[a + 3] = v.w;
    }

    // ---- per-channel scalars (block-uniform; redundant per thread, cheap) ----
    const float s     = fast_sigmoid(log_s[kc]);
    const float alpha = 0.5f * fast_sigmoid(alpha_raw[kc]);
    const float q     = 1.0f - s;
    // q^100 = exp2(100*log2(q)); q in (0,1) strictly, log finite
    const float q100  = __builtin_amdgcn_exp2f(100.0f * __builtin_amdgcn_logf(q));
    const float norm  = (1.0f - q100) + 1e-8f;     // sum of unnormalized geometric weights
    const float w0    = s / norm;                  // normalized weight j=0
    const float c3    = w0 * q100;                 // tail-drop coefficient

    __syncthreads();

    // ---- direct evaluation of M at chunk start (<=100 taps) ----
    // 4 independent FMA chains with q^4-stride weights: chain depth 25, not 100.
    const int t0 = tid * CHUNK;
    float M;
    {
        const float q2 = q * q;
        const float q3 = q2 * q;
        const float q4 = q2 * q2;
        const int jmax  = (t0 >= LEN - 1) ? LEN : (t0 + 1);  // clip at row start
        const int jmax4 = jmax & ~3;
        float m0 = 0.0f, m1 = 0.0f, m2 = 0.0f, m3 = 0.0f;
        float wj = w0;
        int j = 0;
        for (; j < jmax4; j += 4) {
            m0 = fmaf(wj,      fabsf(lx[skew(t0 - j)]),     m0);
            m1 = fmaf(wj * q,  fabsf(lx[skew(t0 - j - 1)]), m1);
            m2 = fmaf(wj * q2, fabsf(lx[skew(t0 - j - 2)]), m2);
            m3 = fmaf(wj * q3, fabsf(lx[skew(t0 - j - 3)]), m3);
            wj *= q4;
        }
        for (; j < jmax; ++j) {
            m0 = fmaf(wj, fabsf(lx[skew(t0 - j)]), m0);
            wj *= q;
        }
        M = (m0 + m1) + (m2 + m3);
    }

    // ---- recursion + epilogue over the thread's 32 elements ----
    float xv = lx[skew(t0)];
    #pragma unroll
    for (int k4 = 0; k4 < CHUNK / 4; ++k4) {
        float4 o;
        float* op = &o.x;
        #pragma unroll
        for (int u = 0; u < 4; ++u) {
            const int k = k4 * 4 + u;
            const int t = t0 + k;
            if (k > 0) {
                xv = lx[skew(t)];
                const int tb = t - LEN;
                const float xb = (tb >= 0) ? fabsf(lx[skew(tb)]) : 0.0f;
                M = q * M + w0 * fabsf(xv) - c3 * xb;
            }
            const float Mc = fmaxf(M, EPS_);
            // Mc^alpha = exp2(alpha * log2(Mc)); Mc >= 1e-6 > 0 so log2 finite
            const float g  = __builtin_amdgcn_exp2f(alpha * __builtin_amdgcn_logf(Mc)) + DELTA_;
            op[u] = xv * __builtin_amdgcn_rcpf(g);   // g >= DELTA = 0.1, rcp safe
        }
        reinterpret_cast<float4*>(orow)[(t0 >> 2) + k4] = o;  // 16B aligned
    }
}

extern "C" void kernel_launch(void* const* d_in, const int* in_sizes, int n_in,
                              void* d_out, int out_size, void* d_ws, size_t ws_size,
                              hipStream_t stream) {
    const float* x         = (const float*)d_in[0];
    const float* alpha_raw = (const float*)d_in[1];
    const float* log_s     = (const float*)d_in[2];
    float* out             = (float*)d_out;
    const int nrows = in_sizes[0] / T;   // B*KC = 4096
    agc_kernel<<<nrows, BLOCK, 0, stream>>>(x, alpha_raw, log_s, out);
}

// Round 3
// 262.771 us; speedup vs baseline: 1.2180x; 1.0154x over previous
//
#include <hip/hip_runtime.h>
#include <hip/hip_fp16.h>
#include <math.h>

// PerBandSoftAGC: out = x / (clip(EMA_FIR(|x|), eps)^alpha + delta)
// EMA FIR (L=100 taps j=0..99, geometric) via exact sliding recursion:
//   M[t] = q*M[t-1] + w0*|x[t]| - w0*q^100 * |x[t-100]|
// R3: LDS row stored as fp16 (17.4 KB vs 33.8 KB) -> 8 blocks/CU = 32 waves/CU
//     (R2 was latency-bound: all pipes ~33% at 4 blocks/CU). Paired __half2
//     LDS reads halve the ds_read count. Skew = +2 halves per 32 keeps half2
//     alignment; compute reads are exact 2-way (free) bank distribution.

constexpr int T      = 8192;
constexpr int KC_    = 128;
constexpr int LEN    = 100;
constexpr int BLOCK  = 256;
constexpr int CHUNK  = 32;          // T / BLOCK
constexpr float EPS_   = 1e-6f;
constexpr float DELTA_ = 0.1f;
constexpr float LOG2E  = 1.4426950408889634f;

// skew: +2 halves per 32 halves; preserves parity so even-element half2 stays 4B aligned
__device__ __forceinline__ int sk(int t) { return t + ((t >> 5) << 1); }

__device__ __forceinline__ float fast_sigmoid(float x) {
    const float e = __builtin_amdgcn_exp2f(-x * LOG2E);
    return __builtin_amdgcn_rcpf(1.0f + e);
}

__device__ __forceinline__ float gain_div(float xv, float M, float alpha) {
    const float Mc = fmaxf(M, EPS_);
    // Mc^alpha = exp2(alpha * log2(Mc)); v_log_f32 is log2, v_exp_f32 is exp2
    const float g  = __builtin_amdgcn_exp2f(alpha * __builtin_amdgcn_logf(Mc)) + DELTA_;
    return xv * __builtin_amdgcn_rcpf(g);   // g >= delta = 0.1, rcp safe
}

__global__ __launch_bounds__(BLOCK, 8) void agc_kernel(
    const float* __restrict__ x,
    const float* __restrict__ alpha_raw,
    const float* __restrict__ log_s,
    float* __restrict__ out)
{
    __shared__ __half lh[T + ((T >> 5) << 1)];   // 8704 halves = 17408 B -> 8 blocks/CU

    const int row = blockIdx.x;
    const int kc  = row & (KC_ - 1);
    const int tid = threadIdx.x;
    const float* __restrict__ xrow = x + (size_t)row * T;
    float* __restrict__ orow       = out + (size_t)row * T;

    // ---- stage row into skewed fp16 LDS (coalesced float4 global reads) ----
    #pragma unroll
    for (int it = 0; it < (T / 4) / BLOCK; ++it) {
        const int i = tid + it * BLOCK;
        const float4 v = reinterpret_cast<const float4*>(xrow)[i];
        const int e = sk(i * 4);        // 4 halves never cross a 32-group
        *reinterpret_cast<__half2*>(&lh[e])     = __float22half2_rn(make_float2(v.x, v.y));
        *reinterpret_cast<__half2*>(&lh[e + 2]) = __float22half2_rn(make_float2(v.z, v.w));
    }

    // ---- per-channel scalars (block-uniform) ----
    const float s     = fast_sigmoid(log_s[kc]);
    const float alpha = 0.5f * fast_sigmoid(alpha_raw[kc]);
    const float q     = 1.0f - s;
    const float q100  = __builtin_amdgcn_exp2f(100.0f * __builtin_amdgcn_logf(q));
    const float norm  = (1.0f - q100) + 1e-8f;   // sum of unnormalized geometric weights
    const float w0    = s / norm;                // normalized weight j=0
    const float c3    = w0 * q100;               // tail-drop coefficient

    __syncthreads();

    const int t0 = tid * CHUNK;

    // paired fp16 read: elements (t, t+1), t even (always within one 32-group)
    auto ld2 = [&](int t) -> float2 {
        return __half22float2(*reinterpret_cast<const __half2*>(&lh[sk(t)]));
    };

    if (t0 >= 128) {
        // ---- full-history path (tid >= 4) ----
        // init: M = sum_{j=1..99} w0*q^j*|x[t0-j]|, paired reads, 2 FMA chains
        float m0 = 0.0f, m1 = 0.0f;
        const float qq = q * q;
        float whi = w0 * q;     // weight for j = 2i+1 (hi half)
        float wlo = whi * q;    // weight for j = 2i+2 (lo half)
        #pragma unroll 7
        for (int i = 0; i < 49; ++i) {          // j = 1..98
            const float2 f = ld2(t0 - 2 * i - 2);
            m0 = fmaf(wlo, fabsf(f.x), m0);
            m1 = fmaf(whi, fabsf(f.y), m1);
            wlo *= qq; whi *= qq;
        }
        {   // j = 99 (hi half of pair at t0-100)
            const float2 f = ld2(t0 - LEN);
            m1 = fmaf(whi, fabsf(f.y), m1);     // whi == w0*q^99 here
        }
        float M = m0 + m1;                      // j=0 tap added at m==0 below

        float o[4];
        #pragma unroll
        for (int m = 0; m < CHUNK / 2; ++m) {
            const float2 xf = ld2(t0 + 2 * m);          // own elements 2m, 2m+1
            const float2 xb = ld2(t0 - LEN + 2 * m);    // tail-drop pair
            if (m == 0) M = fmaf(w0, fabsf(xf.x), M);   // completes init (j=0)
            else        M = fmaf(q, M, fmaf(w0, fabsf(xf.x), -c3 * fabsf(xb.x)));
            o[(2 * m)     & 3] = gain_div(xf.x, M, alpha);
            M = fmaf(q, M, fmaf(w0, fabsf(xf.y), -c3 * fabsf(xb.y)));
            o[(2 * m + 1) & 3] = gain_div(xf.y, M, alpha);
            if (m & 1)
                reinterpret_cast<float4*>(orow)[(t0 >> 2) + (m >> 1)] =
                    make_float4(o[0], o[1], o[2], o[3]);
        }
    } else {
        // ---- row-start path (tid < 4, t0 in {0,32,64,96}): guarded scalar ----
        float M = 0.0f;
        float wj = w0;
        for (int j = 0; j <= t0; ++j) {         // all available taps j=0..t0 (<100)
            M = fmaf(wj, fabsf((float)lh[sk(t0 - j)]), M);
            wj *= q;
        }
        float o[4];
        #pragma unroll
        for (int k = 0; k < CHUNK; ++k) {
            const int t = t0 + k;
            const float xv = (float)lh[sk(t)];
            if (k > 0) {
                const int tb = t - LEN;
                const float xb = (tb >= 0) ? fabsf((float)lh[sk(tb)]) : 0.0f;
                M = fmaf(q, M, fmaf(w0, fabsf(xv), -c3 * xb));
            }
            o[k & 3] = gain_div(xv, M, alpha);
            if ((k & 3) == 3)
                reinterpret_cast<float4*>(orow)[(t0 >> 2) + (k >> 2)] =
                    make_float4(o[0], o[1], o[2], o[3]);
        }
    }
}

extern "C" void kernel_launch(void* const* d_in, const int* in_sizes, int n_in,
                              void* d_out, int out_size, void* d_ws, size_t ws_size,
                              hipStream_t stream) {
    const float* x         = (const float*)d_in[0];
    const float* alpha_raw = (const float*)d_in[1];
    const float* log_s     = (const float*)d_in[2];
    float* out             = (float*)d_out;
    const int nrows = in_sizes[0] / T;   // B*KC = 4096
    agc_kernel<<<nrows, BLOCK, 0, stream>>>(x, alpha_raw, log_s, out);
}